// Round 2
// baseline (592.549 us; speedup 1.0000x reference)
//
#include <hip/hip_runtime.h>
#include <hip/hip_bf16.h>

// MSA: B=8,S=4096,D=1024,H=16,DH=64. Softmax over HEAD axis per token (16x16).
// Pipeline: convert->fp16, fused QKV GEMM (N=3072), MFMA per-token attention,
// out GEMM.
//
// GEMM v3: 256x256 tile, BK=32, 4 LDS dbufs (deep pipeline), 8 waves (2Mx4N).
//   - tile u stages K-tile u+3 (2 gl_lds rounds per phase) -> vmcnt(8) guard
//     is pre-satisfied (~3 tiles of slack). Never drained to 0 in main loop.
//   - 2 phases/tile of 16 MFMA; ds_reads for phase p+1 issued before phase
//     p's MFMA cluster (read-ahead) so lgkm waits cover full-phase-old reads.
//   - BK=32 rows = 64 B -> each frag read is a contiguous 1 KiB wave access:
//     bank-conflict-free WITHOUT swizzle; staging LDS is linear.
//   - 2 raw s_barriers/tile: B_mid (after vmcnt guard, before read-ahead of
//     tile u+1) and B_end (write-after-read guard for staging into dbuf u&3
//     at tile u+1). Both deterministic (no timing races).
//   - s_setprio(1) around MFMA clusters; bijective XCD blockIdx swizzle.

#define DEV static __device__ __forceinline__

typedef __attribute__((ext_vector_type(8))) _Float16 fp16x8;
typedef __attribute__((ext_vector_type(4))) float f32x4;

#define MFMA16(a, b, c) __builtin_amdgcn_mfma_f32_16x16x32_f16(a, b, c, 0, 0, 0)

DEV unsigned short f2h(float f) {
    union { _Float16 h; unsigned short u; } c;
    c.h = (_Float16)f;
    return c.u;
}

DEV void gl_lds16(const void* g, void* l) {
    __builtin_amdgcn_global_load_lds(
        (const __attribute__((address_space(1))) unsigned int*)g,
        (__attribute__((address_space(3))) unsigned int*)l, 16, 0, 0);
}

// ---------------- kernel 0: fp32 -> fp16 conversion / packing ----------------
__global__ __launch_bounds__(256) void k_convert(
    const float* __restrict__ x,
    const float* __restrict__ wq, const float* __restrict__ wk,
    const float* __restrict__ wv, const float* __restrict__ wo,
    const float* __restrict__ bq, const float* __restrict__ bk,
    const float* __restrict__ bv,
    unsigned short* __restrict__ Xb, unsigned short* __restrict__ Wb,
    unsigned short* __restrict__ Wob, float* __restrict__ biasc)
{
    const int NX = 33554432 / 4;   // x float4 chunks
    const int NW = 3145728 / 4;    // wq+wk+wv chunks (262144 each)
    const int NO = 1048576 / 4;    // wo chunks
    const int NB = 3072 / 4;       // bias chunks (256 each)
    const int total = NX + NW + NO + NB;
    for (int c = blockIdx.x * blockDim.x + threadIdx.x; c < total;
         c += gridDim.x * blockDim.x) {
        if (c < NX) {
            float4 v = ((const float4*)x)[c];
            uint2 u;
            u.x = f2h(v.x) | ((unsigned int)f2h(v.y) << 16);
            u.y = f2h(v.z) | ((unsigned int)f2h(v.w) << 16);
            ((uint2*)Xb)[c] = u;
        } else if (c < NX + NW) {
            int e = c - NX;
            const float* w = (e < 262144) ? wq : (e < 524288) ? wk : wv;
            int off = e & 262143;
            float4 v = ((const float4*)w)[off];
            uint2 u;
            u.x = f2h(v.x) | ((unsigned int)f2h(v.y) << 16);
            u.y = f2h(v.z) | ((unsigned int)f2h(v.w) << 16);
            ((uint2*)Wb)[e] = u;
        } else if (c < NX + NW + NO) {
            int e = c - NX - NW;
            float4 v = ((const float4*)wo)[e];
            uint2 u;
            u.x = f2h(v.x) | ((unsigned int)f2h(v.y) << 16);
            u.y = f2h(v.z) | ((unsigned int)f2h(v.w) << 16);
            ((uint2*)Wob)[e] = u;
        } else {
            int e = c - NX - NW - NO;               // 0..767
            const float* b = (e < 256) ? bq : (e < 512) ? bk : bv;
            int off = e & 255;
            ((float4*)biasc)[e] = ((const float4*)b)[off];
        }
    }
}

// ---------------- GEMM: C[M][N] = A[M][K] * B[N][K]^T + bias, K=1024 --------
// Per-K-tile body. MODE 0: steady (stage u+3, vmcnt(8)); MODE 1: u=K/32-3
// (no stage, vmcnt(4)); MODE 2: u=K/32-2 (no stage, vmcnt(0)); MODE 3: last
// tile (no stage/guard/read-ahead/barriers).
template <int MODE>
DEV void g_ktile(
    const unsigned short* rdA_d, const unsigned short* rdB_d,   // dbuf u&3
    const unsigned short* rdA_n, const unsigned short* rdB_n,   // dbuf (u+1)&3
    char* stA0, char* stA1, char* stB0, char* stB1,             // dbuf (u+3)&3
    const unsigned short* gA0, const unsigned short* gA1,       // src at tile u+3
    const unsigned short* gB0, const unsigned short* gB1,
    fp16x8 (&Ac)[8], fp16x8 (&An)[8],
    fp16x8 (&B01c)[2], fp16x8 (&B01n)[2],
    f32x4 (&acc)[8][4])
{
    fp16x8 B23_0, B23_1;
    // ---- phase 0: stage A(u+3), read B23(u), MFMA n in {0,1} ----
    if (MODE == 0) { gl_lds16(gA0, stA0); gl_lds16(gA1, stA1); }
    B23_0 = *(const fp16x8*)(const void*)(rdB_d + 1024);
    B23_1 = *(const fp16x8*)(const void*)(rdB_d + 1536);
    __builtin_amdgcn_sched_barrier(0);
    __builtin_amdgcn_s_setprio(1);
#pragma unroll
    for (int i = 0; i < 8; ++i) {
        acc[i][0] = MFMA16(Ac[i], B01c[0], acc[i][0]);
        acc[i][1] = MFMA16(Ac[i], B01c[1], acc[i][1]);
    }
    __builtin_amdgcn_s_setprio(0);
    __builtin_amdgcn_sched_barrier(0);
    // ---- phase 1: stage B(u+3), guard, B_mid, read-ahead(u+1), MFMA n in {2,3}
    if (MODE == 0) { gl_lds16(gB0, stB0); gl_lds16(gB1, stB1); }
    if (MODE == 0) asm volatile("s_waitcnt vmcnt(8)" ::: "memory");
    if (MODE == 1) asm volatile("s_waitcnt vmcnt(4)" ::: "memory");
    if (MODE == 2) asm volatile("s_waitcnt vmcnt(0)" ::: "memory");
    if (MODE != 3) {
        __builtin_amdgcn_s_barrier();               // B_mid: tile u+1 visible
        asm volatile("" ::: "memory");
#pragma unroll
        for (int i = 0; i < 8; ++i)
            An[i] = *(const fp16x8*)(const void*)(rdA_n + i * 512);
        B01n[0] = *(const fp16x8*)(const void*)(rdB_n + 0);
        B01n[1] = *(const fp16x8*)(const void*)(rdB_n + 512);
    }
    __builtin_amdgcn_sched_barrier(0);
    __builtin_amdgcn_s_setprio(1);
#pragma unroll
    for (int i = 0; i < 8; ++i) {
        acc[i][2] = MFMA16(Ac[i], B23_0, acc[i][2]);
        acc[i][3] = MFMA16(Ac[i], B23_1, acc[i][3]);
    }
    __builtin_amdgcn_s_setprio(0);
    if (MODE != 3) {
        __builtin_amdgcn_s_barrier();               // B_end: WAR guard
        asm volatile("" ::: "memory");
    }
}

template <bool OUT_F16>
__global__ __launch_bounds__(512, 2) void k_gemm256(
    const unsigned short* __restrict__ A,   // [M][1024] fp16
    const unsigned short* __restrict__ B,   // [N][1024] fp16
    const float* __restrict__ bias,         // [N] fp32
    unsigned short* __restrict__ Ch,        // fp16 out (if OUT_F16)
    float* __restrict__ Cf,                 // fp32 out (else)
    int ldc, int nbx)                       // nbx = N/256
{
    __shared__ __align__(16) unsigned short Asx[4][2][4096];  // [dbuf][half][128*32]
    __shared__ __align__(16) unsigned short Bsx[4][2][4096];

    const int tid  = threadIdx.x;
    const int lane = tid & 63;
    const int w    = tid >> 6;
    const int wr   = w >> 2, wc = w & 3;       // 2M x 4N waves
    const int quad = lane >> 4;
    const int lr   = lane & 15;

    // bijective XCD swizzle (gridDim.x % 8 == 0 for both launches)
    const int cpx = gridDim.x >> 3;
    const int id  = (blockIdx.x & 7) * cpx + (blockIdx.x >> 3);
    const int by  = id / nbx, bx = id - by * nbx;
    const int m0  = by * 256, n0 = bx * 256;

    // frag read bases (element offsets; rows are 32 fp16 = 64 B -> each frag
    // read is a contiguous 1 KiB wave access, conflict-free, no swizzle)
    const unsigned short* rdA0 = &Asx[0][wr][0] + lr * 32 + quad * 8;
    const unsigned short* rdB0 = &Bsx[0][wc >> 1][0] + (wc & 1) * 2048 + lr * 32 + quad * 8;
    // staging dests (linear; wave-uniform base + lane*16)
    char* stA_base = (char*)&Asx[0][0][0] + tid * 16;
    char* stB_base = (char*)&Bsx[0][0][0] + tid * 16;
    // staging sources: thread covers row tid>>2 (per half), col (tid&3)*8
    const unsigned short* gA0 = A + (size_t)(m0 + (tid >> 2)) * 1024 + (tid & 3) * 8;
    const unsigned short* gA1 = gA0 + (size_t)128 * 1024;
    const unsigned short* gB0 = B + (size_t)(n0 + (tid >> 2)) * 1024 + (tid & 3) * 8;
    const unsigned short* gB1 = gB0 + (size_t)128 * 1024;

#define RD_A(d) (rdA0 + (d) * 8192)
#define RD_B(d) (rdB0 + (d) * 8192)
#define ST_A(d, h) (stA_base + ((d) * 2 + (h)) * 8192)
#define ST_B(d, h) (stB_base + ((d) * 2 + (h)) * 8192)

    f32x4 acc[8][4];
#pragma unroll
    for (int i = 0; i < 8; ++i)
#pragma unroll
        for (int j = 0; j < 4; ++j) {
            f32x4 z = {0.f, 0.f, 0.f, 0.f};
            acc[i][j] = z;
        }

    // prologue: stage K-tiles 0,1,2 (12 rounds); vmcnt(8) -> tile 0 landed
#pragma unroll
    for (int u = 0; u < 3; ++u) {
        gl_lds16(gA0 + u * 32, ST_A(u, 0));
        gl_lds16(gA1 + u * 32, ST_A(u, 1));
        gl_lds16(gB0 + u * 32, ST_B(u, 0));
        gl_lds16(gB1 + u * 32, ST_B(u, 1));
    }
    asm volatile("s_waitcnt vmcnt(8)" ::: "memory");
    __builtin_amdgcn_s_barrier();
    asm volatile("" ::: "memory");

    // tile-0 frags
    fp16x8 Ar0[8], Ar1[8], B01a[2], B01b[2];
#pragma unroll
    for (int i = 0; i < 8; ++i)
        Ar0[i] = *(const fp16x8*)(const void*)(RD_A(0) + i * 512);
    B01a[0] = *(const fp16x8*)(const void*)(RD_B(0) + 0);
    B01a[1] = *(const fp16x8*)(const void*)(RD_B(0) + 512);

    // main loop: K=1024 -> 32 K-tiles; u=0..27 steady (stage u+3)
    const unsigned short *pA0 = gA0 + 96, *pA1 = gA1 + 96,
                         *pB0 = gB0 + 96, *pB1 = gB1 + 96;
    for (int it = 0; it < 7; ++it) {
        g_ktile<0>(RD_A(0), RD_B(0), RD_A(1), RD_B(1),
                   ST_A(3, 0), ST_A(3, 1), ST_B(3, 0), ST_B(3, 1),
                   pA0, pA1, pB0, pB1, Ar0, Ar1, B01a, B01b, acc);
        g_ktile<0>(RD_A(1), RD_B(1), RD_A(2), RD_B(2),
                   ST_A(0, 0), ST_A(0, 1), ST_B(0, 0), ST_B(0, 1),
                   pA0 + 32, pA1 + 32, pB0 + 32, pB1 + 32, Ar1, Ar0, B01b, B01a, acc);
        g_ktile<0>(RD_A(2), RD_B(2), RD_A(3), RD_B(3),
                   ST_A(1, 0), ST_A(1, 1), ST_B(1, 0), ST_B(1, 1),
                   pA0 + 64, pA1 + 64, pB0 + 64, pB1 + 64, Ar0, Ar1, B01a, B01b, acc);
        g_ktile<0>(RD_A(3), RD_B(3), RD_A(0), RD_B(0),
                   ST_A(2, 0), ST_A(2, 1), ST_B(2, 0), ST_B(2, 1),
                   pA0 + 96, pA1 + 96, pB0 + 96, pB1 + 96, Ar1, Ar0, B01b, B01a, acc);
        pA0 += 128; pA1 += 128; pB0 += 128; pB1 += 128;
    }
    // u=28: stages tile 31 -> dbuf 3
    g_ktile<0>(RD_A(0), RD_B(0), RD_A(1), RD_B(1),
               ST_A(3, 0), ST_A(3, 1), ST_B(3, 0), ST_B(3, 1),
               pA0, pA1, pB0, pB1, Ar0, Ar1, B01a, B01b, acc);
    // u=29: vmcnt(4) -> tile 30 landed
    g_ktile<1>(RD_A(1), RD_B(1), RD_A(2), RD_B(2),
               ST_A(3, 0), ST_A(3, 1), ST_B(3, 0), ST_B(3, 1),
               pA0, pA1, pB0, pB1, Ar1, Ar0, B01b, B01a, acc);
    // u=30: vmcnt(0) -> tile 31 landed
    g_ktile<2>(RD_A(2), RD_B(2), RD_A(3), RD_B(3),
               ST_A(3, 0), ST_A(3, 1), ST_B(3, 0), ST_B(3, 1),
               pA0, pA1, pB0, pB1, Ar0, Ar1, B01a, B01b, acc);
    // u=31: last
    g_ktile<3>(RD_A(3), RD_B(3), RD_A(0), RD_B(0),
               ST_A(3, 0), ST_A(3, 1), ST_B(3, 0), ST_B(3, 1),
               pA0, pA1, pB0, pB1, Ar1, Ar0, B01b, B01a, acc);

#undef RD_A
#undef RD_B
#undef ST_A
#undef ST_B

    // epilogue: C layout col=lane&15, row=quad*4+r
    float bj[4];
#pragma unroll
    for (int j = 0; j < 4; ++j) bj[j] = bias[n0 + wc * 64 + j * 16 + lr];
#pragma unroll
    for (int i = 0; i < 8; ++i) {
        const int mrow = m0 + wr * 128 + i * 16 + quad * 4;
#pragma unroll
        for (int j = 0; j < 4; ++j) {
            const int ncol = n0 + wc * 64 + j * 16 + lr;
#pragma unroll
            for (int r = 0; r < 4; ++r) {
                float v = acc[i][j][r] + bj[j];
                if (OUT_F16)
                    Ch[(size_t)(mrow + r) * ldc + ncol] = f2h(v);
                else
                    Cf[(size_t)(mrow + r) * ldc + ncol] = v;
            }
        }
    }
}

// ---------------- kernel 2: per-token 16x16 head attention via MFMA ---------
__global__ __launch_bounds__(256) void k_attn(
    const unsigned short* __restrict__ qkv,
    unsigned short* __restrict__ Ctx)           // [32768][1024] fp16
{
    __shared__ __align__(16) unsigned short sqk[4][32 * 72];
    __shared__ __align__(16) unsigned short svt[4][64 * 24];
    __shared__ __align__(16) unsigned short spp[4][16 * 24];

    const int tid  = threadIdx.x;
    const int wv   = tid >> 6;
    const int l    = tid & 63;
    const int t    = blockIdx.x * 4 + wv;
    const unsigned short* tok = qkv + (size_t)t * 3072;

    unsigned short* qk = sqk[wv];
    unsigned short* vt = svt[wv];
    unsigned short* pp = spp[wv];

    const int quad = l >> 4;
    const int lr   = l & 15;
    const int row8 = l >> 3;          // 0..7
    const int col8 = (l & 7) * 8;     // 0,8,..,56

#pragma unroll
    for (int i = 0; i < 4; ++i) {
        const int row = i * 8 + row8;
        uint4 u = *(const uint4*)(tok + i * 512 + l * 8);
        *(uint4*)&qk[row * 72 + col8] = u;
    }
#pragma unroll
    for (int i = 0; i < 2; ++i) {
        const int g = i * 8 + row8;
        uint4 u = *(const uint4*)(tok + 2048 + i * 512 + l * 8);
        const unsigned short* hu = (const unsigned short*)&u;
#pragma unroll
        for (int c = 0; c < 8; ++c)
            vt[(col8 + c) * 24 + g] = hu[c];
    }
    asm volatile("s_waitcnt lgkmcnt(0)" ::: "memory");

    f32x4 s = {0.f, 0.f, 0.f, 0.f};
#pragma unroll
    for (int ks = 0; ks < 2; ++ks) {
        fp16x8 aq = *(const fp16x8*)(const void*)&qk[lr * 72 + ks * 32 + quad * 8];
        fp16x8 bk = *(const fp16x8*)(const void*)&qk[(16 + lr) * 72 + ks * 32 + quad * 8];
        s = MFMA16(aq, bk, s);
    }

#pragma unroll
    for (int r = 0; r < 4; ++r) {
        float sv = s[r] * 0.125f;          // 1/sqrt(64)
        float m = sv;
        m = fmaxf(m, __shfl_xor(m, 1, 64));
        m = fmaxf(m, __shfl_xor(m, 2, 64));
        m = fmaxf(m, __shfl_xor(m, 4, 64));
        m = fmaxf(m, __shfl_xor(m, 8, 64));
        float e = __expf(sv - m);
        float su = e;
        su += __shfl_xor(su, 1, 64);
        su += __shfl_xor(su, 2, 64);
        su += __shfl_xor(su, 4, 64);
        su += __shfl_xor(su, 8, 64);
        float p = e * __builtin_amdgcn_rcpf(su);
        pp[(quad * 4 + r) * 24 + lr] = f2h(p);   // P[h][g]
    }
    asm volatile("s_waitcnt lgkmcnt(0)" ::: "memory");

    fp16x8 pa;
    if (quad < 2) {
        pa = *(const fp16x8*)(const void*)&pp[lr * 24 + quad * 8];
    } else {
#pragma unroll
        for (int j = 0; j < 8; ++j) pa[j] = (_Float16)0.f;
    }

    f32x4 c[4];
#pragma unroll
    for (int nb = 0; nb < 4; ++nb) {
        fp16x8 bv;
        if (quad < 2) {
            bv = *(const fp16x8*)(const void*)&vt[(nb * 16 + lr) * 24 + quad * 8];
        } else {
#pragma unroll
            for (int j = 0; j < 8; ++j) bv[j] = (_Float16)0.f;
        }
        f32x4 z = {0.f, 0.f, 0.f, 0.f};
        c[nb] = MFMA16(pa, bv, z);
    }
    asm volatile("s_waitcnt lgkmcnt(0)" ::: "memory");

#pragma unroll
    for (int nb = 0; nb < 4; ++nb)
#pragma unroll
        for (int r = 0; r < 4; ++r)
            qk[(quad * 4 + r) * 72 + nb * 16 + lr] = f2h(c[nb][r]);
    asm volatile("s_waitcnt lgkmcnt(0)" ::: "memory");

    unsigned short* dst = Ctx + (size_t)t * 1024;
#pragma unroll
    for (int i = 0; i < 2; ++i) {
        const int row = i * 8 + row8;
        uint4 u = *(const uint4*)&qk[row * 72 + col8];
        *(uint4*)(dst + row * 64 + col8) = u;
    }
}

// ---------------- launch ----------------------------------------------------
extern "C" void kernel_launch(void* const* d_in, const int* in_sizes, int n_in,
                              void* d_out, int out_size, void* d_ws, size_t ws_size,
                              hipStream_t stream)
{
    (void)in_sizes; (void)n_in; (void)out_size;

    const float* x  = (const float*)d_in[0];
    const float* wq = (const float*)d_in[1];
    const float* bq = (const float*)d_in[2];
    const float* wk = (const float*)d_in[3];
    const float* bk = (const float*)d_in[4];
    const float* wv = (const float*)d_in[5];
    const float* bv = (const float*)d_in[6];
    const float* wo = (const float*)d_in[7];
    const float* bo = (const float*)d_in[8];

    // ws layout (bytes):
    //   QKV  [32768][3072] fp16 : 0          .. 201326592   (192 MiB)
    //   Xb   [32768][1024] fp16 : 201326592  .. 268435456   ( 64 MiB)
    //        (reused as dense Ctx after the QKV GEMM has consumed it)
    //   Wb   [3072][1024]  fp16 : 268435456  .. 274726912   (  6 MiB)
    //   Wob  [1024][1024]  fp16 : 274726912  .. 276824064   (  2 MiB)
    //   bias [3072]        fp32 : 276824064  .. 276836352   ( 12 KiB)
    if (ws_size < 276836352ull) return;

    char* ws = (char*)d_ws;
    unsigned short* QKV  = (unsigned short*)(ws);
    unsigned short* Xb   = (unsigned short*)(ws + 201326592);
    unsigned short* Wb   = (unsigned short*)(ws + 268435456);
    unsigned short* Wob  = (unsigned short*)(ws + 274726912);
    float*          bqkv = (float*)(ws + 276824064);
    unsigned short* Ctx  = Xb;   // Xb dead after QKV GEMM (stream-ordered)

    k_convert<<<2048, 256, 0, stream>>>(x, wq, wk, wv, wo, bq, bk, bv,
                                        Xb, Wb, Wob, bqkv);
    // QKV GEMM: M=32768, N=3072 -> 128x12 = 1536 blocks (%8==0)
    k_gemm256<true><<<1536, 512, 0, stream>>>(
        Xb, Wb, bqkv, QKV, nullptr, 3072, 12);
    k_attn<<<8192, 256, 0, stream>>>(QKV, Ctx);
    // out GEMM: M=32768, N=1024 -> 128x4 = 512 blocks (%8==0)
    k_gemm256<false><<<512, 512, 0, stream>>>(
        Ctx, Wob, bo, nullptr, (float*)d_out, 1024, 4);
}